// Round 7
// baseline (187.382 us; speedup 1.0000x reference)
//
#include <hip/hip_runtime.h>
#include <hip/hip_bf16.h>
#include <math.h>

typedef __bf16 bf16;
typedef __attribute__((ext_vector_type(8))) __bf16 bf16x8;
typedef __attribute__((ext_vector_type(4))) __bf16 bf16x4;
typedef __attribute__((ext_vector_type(4))) float f32x4;

#define B_  2
#define T_  2048
#define C_  1024
#define H_  16
#define HD_ 64
#define WIN_ 256

// async global->LDS, 16B per lane, dest = wave-uniform base + lane*16
#define GLOAD16(g, l)                                                        \
  __builtin_amdgcn_global_load_lds(                                          \
      (const __attribute__((address_space(1))) void*)(g),                    \
      (__attribute__((address_space(3))) void*)(l), 16, 0, 0)

__device__ inline void bar() {
  asm volatile("" ::: "memory");
  __builtin_amdgcn_s_barrier();
  asm volatile("" ::: "memory");
}

__device__ __forceinline__ void keep8(const bf16x8& v) {
  int4 t = __builtin_bit_cast(int4, v);
  asm volatile("" :: "v"(t.x), "v"(t.y), "v"(t.z), "v"(t.w));
}

// ---------------- conversions ----------------

__global__ __launch_bounds__(256) void cvt_f32_bf16_k(const float* __restrict__ in,
                                                      bf16* __restrict__ out) {
  int idx = blockIdx.x * 256 + threadIdx.x;
  const float4 v = ((const float4*)in)[idx];
  bf16x4 o;
  o[0] = (bf16)v.x; o[1] = (bf16)v.y; o[2] = (bf16)v.z; o[3] = (bf16)v.w;
  ((bf16x4*)out)[idx] = o;
}

__global__ __launch_bounds__(256) void transpose_cvt_k(const float* __restrict__ W,
                                                       bf16* __restrict__ WT,
                                                       int K, int N) {
  __shared__ float t[32][33];
  int n0 = blockIdx.x * 32, k0 = blockIdx.y * 32;
  int tx = threadIdx.x, ty = threadIdx.y;
  #pragma unroll
  for (int i = 0; i < 32; i += 8)
    t[ty + i][tx] = W[(size_t)(k0 + ty + i) * N + (n0 + tx)];
  __syncthreads();
  #pragma unroll
  for (int i = 0; i < 32; i += 8)
    WT[(size_t)(n0 + ty + i) * K + (k0 + tx)] = (bf16)t[tx][ty + i];
}

// ---------------- 256x256 8-phase MFMA GEMM body (ablation-gated) ----------------
// ABL bits: 1 = staging(+vmcnt), 2 = ds_read, 4 = MFMA.  Real kernel = 7.

template <int MODE, int ABL>
__device__ __forceinline__ void gemm8p_body(const bf16* __restrict__ A,
                                            const bf16* __restrict__ Bt,
                                            const float* __restrict__ bias,
                                            void* __restrict__ out0,
                                            void* __restrict__ out1,
                                            int M, int N, int K) {
  constexpr bool ST = (ABL & 1) != 0;
  constexpr bool RD = (ABL & 2) != 0;
  constexpr bool MM = (ABL & 4) != 0;

  const int bm = blockIdx.x * 256;
  const int bn = blockIdx.y * 256;
  const int tid  = threadIdx.x;
  const int wid  = tid >> 6;
  const int lane = tid & 63;
  const int wr = wid >> 2;
  const int wc = wid & 3;
  const int lr = lane & 15;
  const int g  = lane >> 4;

  __shared__ bf16 As[2][256 * 64];
  __shared__ bf16 Bs[2][256 * 64];

  f32x4 acc[8][4] = {};

  const int sr = lane >> 3;
  const int sc = ((lane & 7) ^ sr) << 3;
  const bf16* aS = A  + (size_t)(bm + wid * 8 + sr) * K + sc;
  const bf16* bS = Bt + (size_t)(bn + wid * 8 + sr) * K + sc;

  #define STA(p_, q_, u_)                                                    \
    GLOAD16(aS + (size_t)((q_) * 64) * K + (u_) * 64,                        \
            &As[p_][((q_) * 64 + wid * 8) * 64])
  #define STB(p_, q_, u_)                                                    \
    GLOAD16(bS + (size_t)((q_) * 64) * K + (u_) * 64,                        \
            &Bs[p_][((q_) * 64 + wid * 8) * 64])

  const int NT  = K >> 6;
  const int kc0 = ((g    ) ^ (lr & 7)) << 3;
  const int kc1 = ((4 + g) ^ (lr & 7)) << 3;

  if constexpr (ST) {
    STA(0, 0, 0); STA(0, 2, 0); STA(0, 1, 0); STA(0, 3, 0);
    STB(0, 0, 0); STB(0, 1, 0); STB(0, 2, 0); STB(0, 3, 0);
    STA(1, 0, 1); STA(1, 2, 1);
    asm volatile("s_waitcnt vmcnt(2)" ::: "memory");
  } else {
    // touch LDS so ds_reads can't be folded to undef
    As[0][tid] = (bf16)0.f; Bs[0][tid] = (bf16)0.f;
  }
  bar();

  #define MFMA16(mb, a0_, a1_, a2_, a3_)                                     \
    do {                                                                     \
      __builtin_amdgcn_s_setprio(1);                                         \
      _Pragma("unroll")                                                      \
      for (int n = 0; n < 4; ++n) {                                          \
        acc[(mb) + 0][n] = __builtin_amdgcn_mfma_f32_16x16x32_bf16(a0_, bv[n], acc[(mb) + 0][n], 0, 0, 0); \
        acc[(mb) + 1][n] = __builtin_amdgcn_mfma_f32_16x16x32_bf16(a1_, bv[n], acc[(mb) + 1][n], 0, 0, 0); \
        acc[(mb) + 2][n] = __builtin_amdgcn_mfma_f32_16x16x32_bf16(a2_, bv[n], acc[(mb) + 2][n], 0, 0, 0); \
        acc[(mb) + 3][n] = __builtin_amdgcn_mfma_f32_16x16x32_bf16(a3_, bv[n], acc[(mb) + 3][n], 0, 0, 0); \
      }                                                                      \
      __builtin_amdgcn_s_setprio(0);                                         \
    } while (0)

  for (int u = 0; u < NT; ++u) {
    const int p  = u & 1;
    const int pn = p ^ 1;
    const bf16* Ar = &As[p][(wr * 128 + lr) * 64];
    const bf16* Br = &Bs[p][(wc * 64  + lr) * 64];
    bf16x8 bv[4], a0, a1, a2, a3;

    // ---- P1 ----
    if constexpr (RD) {
      #pragma unroll
      for (int n = 0; n < 4; ++n) bv[n] = *(const bf16x8*)(Br + n * 1024 + kc0);
      a0 = *(const bf16x8*)(Ar + 0 * 1024 + kc0);
      a1 = *(const bf16x8*)(Ar + 1 * 1024 + kc0);
      a2 = *(const bf16x8*)(Ar + 2 * 1024 + kc0);
      a3 = *(const bf16x8*)(Ar + 3 * 1024 + kc0);
    }
    if constexpr (ST) { if (u + 1 < NT) { STA(pn, 1, u + 1); STA(pn, 3, u + 1); } }
    bar();
    if constexpr (MM) MFMA16(0, a0, a1, a2, a3);
    else if constexpr (RD) {
      keep8(bv[0]); keep8(bv[1]); keep8(bv[2]); keep8(bv[3]);
      keep8(a0); keep8(a1); keep8(a2); keep8(a3);
    }
    if constexpr (ST) {
      if (u + 1 < NT) asm volatile("s_waitcnt vmcnt(8)" ::: "memory");
      else            asm volatile("s_waitcnt vmcnt(0)" ::: "memory");
    }
    bar();

    // ---- P2 ----
    if constexpr (RD) {
      a0 = *(const bf16x8*)(Ar + 4 * 1024 + kc0);
      a1 = *(const bf16x8*)(Ar + 5 * 1024 + kc0);
      a2 = *(const bf16x8*)(Ar + 6 * 1024 + kc0);
      a3 = *(const bf16x8*)(Ar + 7 * 1024 + kc0);
    }
    if constexpr (ST) { if (u + 1 < NT) { STB(pn, 0, u + 1); STB(pn, 1, u + 1); } }
    bar();
    if constexpr (MM) MFMA16(4, a0, a1, a2, a3);
    else if constexpr (RD) { keep8(a0); keep8(a1); keep8(a2); keep8(a3); }
    bar();

    // ---- P3 ----
    if constexpr (RD) {
      #pragma unroll
      for (int n = 0; n < 4; ++n) bv[n] = *(const bf16x8*)(Br + n * 1024 + kc1);
      a0 = *(const bf16x8*)(Ar + 0 * 1024 + kc1);
      a1 = *(const bf16x8*)(Ar + 1 * 1024 + kc1);
      a2 = *(const bf16x8*)(Ar + 2 * 1024 + kc1);
      a3 = *(const bf16x8*)(Ar + 3 * 1024 + kc1);
    }
    if constexpr (ST) { if (u + 1 < NT) { STB(pn, 2, u + 1); STB(pn, 3, u + 1); } }
    bar();
    if constexpr (MM) MFMA16(0, a0, a1, a2, a3);
    else if constexpr (RD) {
      keep8(bv[0]); keep8(bv[1]); keep8(bv[2]); keep8(bv[3]);
      keep8(a0); keep8(a1); keep8(a2); keep8(a3);
    }
    bar();

    // ---- P4 ----
    if constexpr (RD) {
      a0 = *(const bf16x8*)(Ar + 4 * 1024 + kc1);
      a1 = *(const bf16x8*)(Ar + 5 * 1024 + kc1);
      a2 = *(const bf16x8*)(Ar + 6 * 1024 + kc1);
      a3 = *(const bf16x8*)(Ar + 7 * 1024 + kc1);
    }
    if constexpr (ST) { if (u + 2 < NT) { STA(p, 0, u + 2); STA(p, 2, u + 2); } }
    bar();
    if constexpr (MM) MFMA16(4, a0, a1, a2, a3);
    else if constexpr (RD) { keep8(a0); keep8(a1); keep8(a2); keep8(a3); }
    if constexpr (ST) {
      if (u + 2 < NT) asm volatile("s_waitcnt vmcnt(2)" ::: "memory");
      else            asm volatile("s_waitcnt vmcnt(0)" ::: "memory");
    }
    bar();
  }
  #undef MFMA16
  #undef STA
  #undef STB

  const int orow = g * 4;
  #pragma unroll
  for (int n = 0; n < 4; ++n) {
    const int nbase = bn + wc * 64 + n * 16;
    const int gn = nbase + lr;
    const float bv_ = bias[gn];
    #pragma unroll
    for (int m = 0; m < 8; ++m) {
      const int gm0 = bm + wr * 128 + m * 16 + orow;
      if (MODE == 0) {
        #pragma unroll
        for (int r = 0; r < 4; ++r)
          ((float*)out0)[(size_t)(gm0 + r) * N + gn] = acc[m][n][r] + bv_;
      } else {
        if (nbase < 2 * C_) {
          #pragma unroll
          for (int r = 0; r < 4; ++r)
            ((bf16*)out0)[(size_t)(gm0 + r) * (2 * C_) + gn] = (bf16)(acc[m][n][r] + bv_);
        } else {
          const int vcol = gn - 2 * C_;
          const int h = vcol >> 6, d = vcol & 63;
          const int b = gm0 >> 11, tok = gm0 & (T_ - 1);
          bf16x4 o;
          #pragma unroll
          for (int r = 0; r < 4; ++r) o[r] = (bf16)(acc[m][n][r] + bv_);
          *(bf16x4*)&((bf16*)out1)[(((size_t)b * H_ + h) * HD_ + d) * T_ + tok] = o;
        }
      }
    }
  }
}

__global__ __launch_bounds__(512, 2) void qkv8p_full_k(const bf16* A, const bf16* Bt,
    const float* bias, void* out0, void* out1, int M, int N, int K) {
  gemm8p_body<2, 7>(A, Bt, bias, out0, out1, M, N, K);
}
__global__ __launch_bounds__(512, 2) void diag_stage_k(const bf16* A, const bf16* Bt,
    const float* bias, void* out0, void* out1, int M, int N, int K) {
  gemm8p_body<2, 1>(A, Bt, bias, out0, out1, M, N, K);
}
__global__ __launch_bounds__(512, 2) void diag_nomm_k(const bf16* A, const bf16* Bt,
    const float* bias, void* out0, void* out1, int M, int N, int K) {
  gemm8p_body<2, 3>(A, Bt, bias, out0, out1, M, N, K);
}
__global__ __launch_bounds__(512, 2) void diag_nost_k(const bf16* A, const bf16* Bt,
    const float* bias, void* out0, void* out1, int M, int N, int K) {
  gemm8p_body<2, 6>(A, Bt, bias, out0, out1, M, N, K);
}

// ---------------- deep-pipelined GEMM (proj, 128x128) ----------------

template <int TM, int TN, int WM, int WN, int MODE>
__global__ __launch_bounds__(WM * WN * 64, 2)
void gemm_dp_k(const bf16* __restrict__ A, const bf16* __restrict__ Bt,
               const float* __restrict__ bias,
               void* __restrict__ out0, void* __restrict__ out1,
               int M, int N, int K) {
  constexpr int NW    = WM * WN;
  constexpr int WROWS = TM / WM;
  constexpr int WCOLS = TN / WN;
  constexpr int FM    = WROWS / 16;
  constexpr int FN    = WCOLS / 16;
  constexpr int CA    = TM / 16 / NW;
  constexpr int CB    = TN / 16 / NW;

  const int bm = blockIdx.x * TM;
  const int bn = blockIdx.y * TN;
  const int tid  = threadIdx.x;
  const int wid  = tid >> 6;
  const int lane = tid & 63;
  const int wr = wid / WN;
  const int wc = wid % WN;
  const int lr = lane & 15;
  const int g  = lane >> 4;

  __shared__ bf16 As[4][TM][32];
  __shared__ bf16 Bs[4][TN][32];

  f32x4 acc[FM][FN] = {};

  const int rloc = lane >> 2;
  const int scol = (((lane & 3) ^ (rloc & 3))) * 8;
  const bf16* aSrc = A  + (size_t)(bm + wid * CA * 16 + rloc) * K + scol;
  const bf16* bSrc = Bt + (size_t)(bn + wid * CB * 16 + rloc) * K + scol;

  #define STAGE_DP(buf, kt)                                                   \
    do {                                                                      \
      _Pragma("unroll")                                                       \
      for (int i = 0; i < CA; ++i)                                            \
        GLOAD16(aSrc + (size_t)(i * 16) * K + (kt) * 32,                      \
                &As[buf][(wid * CA + i) * 16][0]);                            \
      _Pragma("unroll")                                                       \
      for (int i = 0; i < CB; ++i)                                            \
        GLOAD16(bSrc + (size_t)(i * 16) * K + (kt) * 32,                      \
                &Bs[buf][(wid * CB + i) * 16][0]);                            \
    } while (0)

  const int NT = K >> 5;
  const int kc = (g ^ (lr & 3)) * 8;

  STAGE_DP(0, 0);
  STAGE_DP(1, 1);

  for (int t = 0; t < NT; ++t) {
    const int buf = t & 3;
    if (t + 2 < NT) {
      STAGE_DP((t + 2) & 3, t + 2);
      asm volatile("s_waitcnt vmcnt(8)" ::: "memory");
    } else if (t + 1 < NT) {
      asm volatile("s_waitcnt vmcnt(4)" ::: "memory");
    } else {
      asm volatile("s_waitcnt vmcnt(0)" ::: "memory");
    }
    __builtin_amdgcn_s_barrier();
    asm volatile("" ::: "memory");

    bf16x8 af[FM], bfv[FN];
    #pragma unroll
    for (int m = 0; m < FM; ++m)
      af[m] = *(const bf16x8*)&As[buf][wr * WROWS + m * 16 + lr][kc];
    #pragma unroll
    for (int n = 0; n < FN; ++n)
      bfv[n] = *(const bf16x8*)&Bs[buf][wc * WCOLS + n * 16 + lr][kc];

    __builtin_amdgcn_s_setprio(1);
    #pragma unroll
    for (int m = 0; m < FM; ++m)
      #pragma unroll
      for (int n = 0; n < FN; ++n)
        acc[m][n] = __builtin_amdgcn_mfma_f32_16x16x32_bf16(af[m], bfv[n], acc[m][n], 0, 0, 0);
    __builtin_amdgcn_s_setprio(0);
  }
  #undef STAGE_DP

  const int orow = g * 4;
  #pragma unroll
  for (int n = 0; n < FN; ++n) {
    const int gn = bn + wc * WCOLS + n * 16 + lr;
    const float bv = bias[gn];
    #pragma unroll
    for (int m = 0; m < FM; ++m) {
      const int gm0 = bm + wr * WROWS + m * 16 + orow;
      if (MODE == 0) {
        #pragma unroll
        for (int r = 0; r < 4; ++r)
          ((float*)out0)[(size_t)(gm0 + r) * N + gn] = acc[m][n][r] + bv;
      }
    }
  }
}

// ---------------- windowed flash attention (MFMA) ----------------

__global__ __launch_bounds__(256) void attn_mfma_k(const bf16* __restrict__ qk,
                                                   const bf16* __restrict__ vt,
                                                   bf16* __restrict__ y) {
  const int q0 = blockIdx.x * 64;
  const int h  = blockIdx.y;
  const int b  = blockIdx.z;
  const int tid  = threadIdx.x;
  const int wid  = tid >> 6;
  const int lane = tid & 63;
  const int lr = lane & 15;
  const int g  = lane >> 4;

  __shared__ bf16 Ks[64][72];
  __shared__ bf16 Vs[64][72];
  __shared__ bf16 Ps[4][16][72];

  const int qrow = q0 + wid * 16 + lr;
  const bf16* qptr = qk + ((size_t)(b * T_ + qrow)) * (2 * C_) + h * HD_;
  bf16x8 qf[2];
  qf[0] = *(const bf16x8*)(qptr + g * 8);
  qf[1] = *(const bf16x8*)(qptr + 32 + g * 8);

  float m = -1e30f, l = 0.f;
  f32x4 yacc[4] = {};

  const int kt_lo = (blockIdx.x >= 4) ? (int)blockIdx.x - 4 : 0;
  for (int kt = kt_lo; kt <= (int)blockIdx.x; ++kt) {
    __syncthreads();
    #pragma unroll
    for (int i = 0; i < 2; ++i) {
      int cc = tid + i * 256;
      int rr = cc >> 3;
      int c0 = (cc & 7) * 8;
      *(bf16x8*)&Ks[rr][c0] = *(const bf16x8*)&qk[((size_t)(b * T_) + kt * 64 + rr) * (2 * C_) + C_ + h * HD_ + c0];
      *(bf16x8*)&Vs[rr][c0] = *(const bf16x8*)&vt[(((size_t)b * H_ + h) * HD_ + rr) * T_ + kt * 64 + c0];
    }
    __syncthreads();

    f32x4 sacc[4] = {};
    #pragma unroll
    for (int t = 0; t < 4; ++t)
      #pragma unroll
      for (int s = 0; s < 2; ++s)
        sacc[t] = __builtin_amdgcn_mfma_f32_16x16x32_bf16(
            *(const bf16x8*)&Ks[t * 16 + lr][s * 32 + g * 8], qf[s], sacc[t], 0, 0, 0);

    float pv[4][4];
    float rmax = -1e30f;
    #pragma unroll
    for (int t = 0; t < 4; ++t)
      #pragma unroll
      for (int r = 0; r < 4; ++r) {
        const int key = kt * 64 + t * 16 + g * 4 + r;
        const bool valid = (key <= qrow) && (qrow - key <= WIN_);
        const float sv = valid ? sacc[t][r] * 0.125f : -__builtin_inff();
        pv[t][r] = sv;
        rmax = fmaxf(rmax, sv);
      }
    rmax = fmaxf(rmax, __shfl_xor(rmax, 16));
    rmax = fmaxf(rmax, __shfl_xor(rmax, 32));

    const float mnew = fmaxf(m, rmax);
    const float alpha = __expf(m - mnew);
    m = mnew;
    float lsum = 0.f;
    #pragma unroll
    for (int t = 0; t < 4; ++t)
      #pragma unroll
      for (int r = 0; r < 4; ++r) {
        const float e = __expf(pv[t][r] - mnew);
        pv[t][r] = e;
        lsum += e;
      }
    lsum += __shfl_xor(lsum, 16);
    lsum += __shfl_xor(lsum, 32);
    l = l * alpha + lsum;

    #pragma unroll
    for (int t = 0; t < 4; ++t) {
      bf16x4 pk;
      #pragma unroll
      for (int r = 0; r < 4; ++r) pk[r] = (bf16)pv[t][r];
      *(bf16x4*)&Ps[wid][lr][t * 16 + g * 4] = pk;
    }

    float al[4];
    #pragma unroll
    for (int r = 0; r < 4; ++r) al[r] = __shfl(alpha, g * 4 + r);
    #pragma unroll
    for (int t = 0; t < 4; ++t)
      #pragma unroll
      for (int r = 0; r < 4; ++r) yacc[t][r] *= al[r];

    bf16x8 pf[2];
    pf[0] = *(const bf16x8*)&Ps[wid][lr][g * 8];
    pf[1] = *(const bf16x8*)&Ps[wid][lr][32 + g * 8];
    #pragma unroll
    for (int t = 0; t < 4; ++t)
      #pragma unroll
      for (int s = 0; s < 2; ++s)
        yacc[t] = __builtin_amdgcn_mfma_f32_16x16x32_bf16(
            pf[s], *(const bf16x8*)&Vs[t * 16 + lr][s * 32 + g * 8], yacc[t], 0, 0, 0);
  }

  float li[4];
  #pragma unroll
  for (int r = 0; r < 4; ++r) li[r] = 1.f / __shfl(l, g * 4 + r);
  #pragma unroll
  for (int t = 0; t < 4; ++t)
    #pragma unroll
    for (int r = 0; r < 4; ++r) {
      const int tok = q0 + wid * 16 + g * 4 + r;
      y[((size_t)(b * T_ + tok)) * C_ + h * HD_ + t * 16 + lr] = (bf16)(yacc[t][r] * li[r]);
    }
}

// ---------------- launch ----------------

extern "C" void kernel_launch(void* const* d_in, const int* in_sizes, int n_in,
                              void* d_out, int out_size, void* d_ws, size_t ws_size,
                              hipStream_t stream) {
  const float* x     = (const float*)d_in[0];
  const float* Wqkv  = (const float*)d_in[1];
  const float* bqkv  = (const float*)d_in[2];
  const float* Wproj = (const float*)d_in[3];
  const float* bproj = (const float*)d_in[4];
  float* out = (float*)d_out;

  const size_t SZ_QK  = (size_t)B_ * T_ * 2 * C_ * sizeof(bf16);
  const size_t SZ_VT  = (size_t)B_ * H_ * HD_ * T_ * sizeof(bf16);
  const size_t SZ_XB  = (size_t)B_ * T_ * C_ * sizeof(bf16);
  const size_t SZ_WQT = (size_t)3 * C_ * C_ * sizeof(bf16);
  const size_t SZ_WPT = (size_t)C_ * C_ * sizeof(bf16);
  const size_t NEED   = SZ_QK + SZ_VT + SZ_XB + SZ_WQT + SZ_WPT + SZ_XB;
  if (ws_size < NEED) return;

  char* ws = (char*)d_ws;
  bf16* qkb    = (bf16*)(ws);
  bf16* vtb    = (bf16*)(ws + SZ_QK);
  bf16* xb     = (bf16*)(ws + SZ_QK + SZ_VT);
  bf16* wqkvT  = (bf16*)(ws + SZ_QK + SZ_VT + SZ_XB);
  bf16* wprojT = (bf16*)(ws + SZ_QK + SZ_VT + SZ_XB + SZ_WQT);
  bf16* yb     = (bf16*)(ws + SZ_QK + SZ_VT + SZ_XB + SZ_WQT + SZ_WPT);

  cvt_f32_bf16_k<<<4096, 256, 0, stream>>>(x, xb);
  transpose_cvt_k<<<dim3(3 * C_ / 32, C_ / 32), dim3(32, 8), 0, stream>>>(Wqkv, wqkvT, C_, 3 * C_);
  transpose_cvt_k<<<dim3(C_ / 32, C_ / 32), dim3(32, 8), 0, stream>>>(Wproj, wprojT, C_, C_);

  const dim3 qgrid((B_ * T_) / 256, (3 * C_) / 256);

  // ---- diagnostics (outputs overwritten by the real qkv below) ----
  diag_stage_k<<<qgrid, 512, 0, stream>>>(xb, wqkvT, bqkv, qkb, vtb, B_ * T_, 3 * C_, C_);
  diag_nomm_k <<<qgrid, 512, 0, stream>>>(xb, wqkvT, bqkv, qkb, vtb, B_ * T_, 3 * C_, C_);
  diag_nost_k <<<qgrid, 512, 0, stream>>>(xb, wqkvT, bqkv, qkb, vtb, B_ * T_, 3 * C_, C_);

  // ---- real qkv ----
  qkv8p_full_k<<<qgrid, 512, 0, stream>>>(xb, wqkvT, bqkv, qkb, vtb, B_ * T_, 3 * C_, C_);

  attn_mfma_k<<<dim3(T_ / 64, H_, B_), 256, 0, stream>>>(qkb, vtb, yb);

  gemm_dp_k<128, 128, 2, 2, 0><<<dim3((B_ * T_) / 128, C_ / 128), 256, 0, stream>>>(
      yb, wprojT, bproj, out, nullptr, B_ * T_, C_, C_);
}

// Round 8
// 93.543 us; speedup vs baseline: 2.0032x; 2.0032x over previous
//
#include <hip/hip_runtime.h>
#include <hip/hip_bf16.h>
#include <math.h>

typedef __bf16 bf16;
typedef __attribute__((ext_vector_type(8))) __bf16 bf16x8;
typedef __attribute__((ext_vector_type(4))) __bf16 bf16x4;
typedef __attribute__((ext_vector_type(4))) float f32x4;

#define B_  2
#define T_  2048
#define C_  1024
#define H_  16
#define HD_ 64
#define WIN_ 256

// async global->LDS, 16B per lane, dest = wave-uniform base + lane*16
#define GLOAD16(g, l)                                                        \
  __builtin_amdgcn_global_load_lds(                                          \
      (const __attribute__((address_space(1))) void*)(g),                    \
      (__attribute__((address_space(3))) void*)(l), 16, 0, 0)

__device__ inline void bar() {
  asm volatile("" ::: "memory");
  __builtin_amdgcn_s_barrier();
  asm volatile("" ::: "memory");
}

// ---------------- conversions ----------------

__global__ __launch_bounds__(256) void cvt_f32_bf16_k(const float* __restrict__ in,
                                                      bf16* __restrict__ out) {
  int idx = blockIdx.x * 256 + threadIdx.x;
  const float4 v = ((const float4*)in)[idx];
  bf16x4 o;
  o[0] = (bf16)v.x; o[1] = (bf16)v.y; o[2] = (bf16)v.z; o[3] = (bf16)v.w;
  ((bf16x4*)out)[idx] = o;
}

__global__ __launch_bounds__(256) void transpose_cvt_k(const float* __restrict__ W,
                                                       bf16* __restrict__ WT,
                                                       int K, int N) {
  __shared__ float t[32][33];
  int n0 = blockIdx.x * 32, k0 = blockIdx.y * 32;
  int tx = threadIdx.x, ty = threadIdx.y;
  #pragma unroll
  for (int i = 0; i < 32; i += 8)
    t[ty + i][tx] = W[(size_t)(k0 + ty + i) * N + (n0 + tx)];
  __syncthreads();
  #pragma unroll
  for (int i = 0; i < 32; i += 8)
    WT[(size_t)(n0 + ty + i) * K + (k0 + tx)] = (bf16)t[tx][ty + i];
}

// ---------------- 256x192 8-phase MFMA GEMM (qkv; full grid fill) ----------------
// C = A[M][K] * Bt[N][K]^T + bias. BK=64, 8 waves (2Mx4N), per-wave 128x48.
// Grid (M/256) x (N/192) = 16x16 = 256 blocks = exactly 1 per CU.
// LDS: A 2x256x64 + B 2x192x64 = 112 KiB, XOR-swizzled (inverse on global src).
// Staging: 7 x 1KB gload_lds per wave per K-tile (A chunks 0..31, B 0..23),
// all issued in P1 for tile u+1; single vmcnt(0) at end-P4 (~3.5 phases cover).
// MODE 2 epilogue: cols [0,2C) -> bf16 out0 stride 2C; [2C,3C) -> V^T out1.

template <int MODE>
__global__ __launch_bounds__(512) void gemm8p_k(const bf16* __restrict__ A,
                                                const bf16* __restrict__ Bt,
                                                const float* __restrict__ bias,
                                                void* __restrict__ out0,
                                                void* __restrict__ out1,
                                                int M, int N, int K) {
  const int bm = blockIdx.x * 256;
  const int bn = blockIdx.y * 192;
  const int tid  = threadIdx.x;
  const int wid  = tid >> 6;
  const int lane = tid & 63;
  const int wr = wid >> 2;            // 0..1
  const int wc = wid & 3;             // 0..3
  const int lr = lane & 15;
  const int g  = lane >> 4;

  __shared__ bf16 As[2][256 * 64];    // 64 KiB
  __shared__ bf16 Bs[2][192 * 64];    // 48 KiB

  f32x4 acc[8][3] = {};

  // staging: 1KB chunk = 8 rows x 128B; lane -> row lane>>3,
  // global 16B chunk (lane&7)^(lane>>3); LDS dest linear (base + lane*16).
  const int sr = lane >> 3;
  const int sc = ((lane & 7) ^ sr) << 3;            // bf16 col of 16B piece

  // chunks: c in [0,32) -> A rows c*8.. ; c in [32,56) -> B rows (c-32)*8..
  #define STAGE7(pn_, u_)                                                    \
    do {                                                                     \
      _Pragma("unroll")                                                      \
      for (int i = 0; i < 7; ++i) {                                          \
        const int c = wid * 7 + i;                                           \
        if (c < 32) {                                                        \
          GLOAD16(A + (size_t)(bm + c * 8 + sr) * K + (u_) * 64 + sc,        \
                  &As[pn_][c * 8 * 64]);                                     \
        } else {                                                             \
          GLOAD16(Bt + (size_t)(bn + (c - 32) * 8 + sr) * K + (u_) * 64 + sc,\
                  &Bs[pn_][(c - 32) * 8 * 64]);                              \
        }                                                                    \
      }                                                                      \
    } while (0)

  const int NT  = K >> 6;
  // read-side swizzle: LDS[r][j] = global[r][j ^ (r&7)]; fragment rows have
  // r&7 == lr&7 (row bases are multiples of 16).
  const int kc0 = ((g    ) ^ (lr & 7)) << 3;
  const int kc1 = ((4 + g) ^ (lr & 7)) << 3;

  // ---- prologue: tile 0 ----
  STAGE7(0, 0);
  asm volatile("s_waitcnt vmcnt(0)" ::: "memory");
  __builtin_amdgcn_s_barrier();
  asm volatile("" ::: "memory");

  #define MFMA12(mb, a0_, a1_, a2_, a3_)                                     \
    do {                                                                     \
      __builtin_amdgcn_s_setprio(1);                                         \
      _Pragma("unroll")                                                      \
      for (int n = 0; n < 3; ++n) {                                          \
        acc[(mb) + 0][n] = __builtin_amdgcn_mfma_f32_16x16x32_bf16(a0_, bv[n], acc[(mb) + 0][n], 0, 0, 0); \
        acc[(mb) + 1][n] = __builtin_amdgcn_mfma_f32_16x16x32_bf16(a1_, bv[n], acc[(mb) + 1][n], 0, 0, 0); \
        acc[(mb) + 2][n] = __builtin_amdgcn_mfma_f32_16x16x32_bf16(a2_, bv[n], acc[(mb) + 2][n], 0, 0, 0); \
        acc[(mb) + 3][n] = __builtin_amdgcn_mfma_f32_16x16x32_bf16(a3_, bv[n], acc[(mb) + 3][n], 0, 0, 0); \
      }                                                                      \
      __builtin_amdgcn_s_setprio(0);                                         \
    } while (0)

  for (int u = 0; u < NT; ++u) {
    const int p  = u & 1;
    const int pn = p ^ 1;
    const bf16* Ar = &As[p][(wr * 128 + lr) * 64];
    const bf16* Br = &Bs[p][(wc * 48  + lr) * 64];
    bf16x8 bv[3], a0, a1, a2, a3;

    // ---- P1: read b[0..2]k0 + a[0..3]k0 ; issue 7 gloads for u+1 ----
    #pragma unroll
    for (int n = 0; n < 3; ++n) bv[n] = *(const bf16x8*)(Br + n * 1024 + kc0);
    a0 = *(const bf16x8*)(Ar + 0 * 1024 + kc0);
    a1 = *(const bf16x8*)(Ar + 1 * 1024 + kc0);
    a2 = *(const bf16x8*)(Ar + 2 * 1024 + kc0);
    a3 = *(const bf16x8*)(Ar + 3 * 1024 + kc0);
    if (u + 1 < NT) STAGE7(pn, u + 1);
    bar();
    MFMA12(0, a0, a1, a2, a3);
    bar();

    // ---- P2: a[4..7]k0 ----
    a0 = *(const bf16x8*)(Ar + 4 * 1024 + kc0);
    a1 = *(const bf16x8*)(Ar + 5 * 1024 + kc0);
    a2 = *(const bf16x8*)(Ar + 6 * 1024 + kc0);
    a3 = *(const bf16x8*)(Ar + 7 * 1024 + kc0);
    bar();
    MFMA12(4, a0, a1, a2, a3);
    bar();

    // ---- P3: b[0..2]k1 + a[0..3]k1 ----
    #pragma unroll
    for (int n = 0; n < 3; ++n) bv[n] = *(const bf16x8*)(Br + n * 1024 + kc1);
    a0 = *(const bf16x8*)(Ar + 0 * 1024 + kc1);
    a1 = *(const bf16x8*)(Ar + 1 * 1024 + kc1);
    a2 = *(const bf16x8*)(Ar + 2 * 1024 + kc1);
    a3 = *(const bf16x8*)(Ar + 3 * 1024 + kc1);
    bar();
    MFMA12(0, a0, a1, a2, a3);
    bar();

    // ---- P4: a[4..7]k1 ; drain u+1 loads (issued 3.5 phases ago) ----
    a0 = *(const bf16x8*)(Ar + 4 * 1024 + kc1);
    a1 = *(const bf16x8*)(Ar + 5 * 1024 + kc1);
    a2 = *(const bf16x8*)(Ar + 6 * 1024 + kc1);
    a3 = *(const bf16x8*)(Ar + 7 * 1024 + kc1);
    bar();
    MFMA12(4, a0, a1, a2, a3);
    asm volatile("s_waitcnt vmcnt(0)" ::: "memory");
    bar();
  }
  #undef MFMA12
  #undef STAGE7

  // ---- epilogue: D elem (reg r, lane l) -> row=(l>>4)*4+r, col=l&15 ----
  const int orow = g * 4;
  #pragma unroll
  for (int n = 0; n < 3; ++n) {
    const int nbase = bn + wc * 48 + n * 16;
    const int gn = nbase + lr;
    const float bv_ = bias[gn];
    #pragma unroll
    for (int m = 0; m < 8; ++m) {
      const int gm0 = bm + wr * 128 + m * 16 + orow;
      if (MODE == 0) {
        #pragma unroll
        for (int r = 0; r < 4; ++r)
          ((float*)out0)[(size_t)(gm0 + r) * N + gn] = acc[m][n][r] + bv_;
      } else { // MODE 2
        if (nbase < 2 * C_) {
          #pragma unroll
          for (int r = 0; r < 4; ++r)
            ((bf16*)out0)[(size_t)(gm0 + r) * (2 * C_) + gn] = (bf16)(acc[m][n][r] + bv_);
        } else {
          const int vcol = gn - 2 * C_;
          const int h = vcol >> 6, d = vcol & 63;
          const int b = gm0 >> 11, tok = gm0 & (T_ - 1);   // gm0 % 4 == 0
          bf16x4 o;
          #pragma unroll
          for (int r = 0; r < 4; ++r) o[r] = (bf16)(acc[m][n][r] + bv_);
          *(bf16x4*)&((bf16*)out1)[(((size_t)b * H_ + h) * HD_ + d) * T_ + tok] = o;
        }
      }
    }
  }
}

// ---------------- deep-pipelined GEMM (proj, 128x128) ----------------

template <int TM, int TN, int WM, int WN, int MODE>
__global__ __launch_bounds__(WM * WN * 64, 2)
void gemm_dp_k(const bf16* __restrict__ A, const bf16* __restrict__ Bt,
               const float* __restrict__ bias,
               void* __restrict__ out0, void* __restrict__ out1,
               int M, int N, int K) {
  constexpr int NW    = WM * WN;
  constexpr int WROWS = TM / WM;
  constexpr int WCOLS = TN / WN;
  constexpr int FM    = WROWS / 16;
  constexpr int FN    = WCOLS / 16;
  constexpr int CA    = TM / 16 / NW;
  constexpr int CB    = TN / 16 / NW;

  const int bm = blockIdx.x * TM;
  const int bn = blockIdx.y * TN;
  const int tid  = threadIdx.x;
  const int wid  = tid >> 6;
  const int lane = tid & 63;
  const int wr = wid / WN;
  const int wc = wid % WN;
  const int lr = lane & 15;
  const int g  = lane >> 4;

  __shared__ bf16 As[4][TM][32];
  __shared__ bf16 Bs[4][TN][32];

  f32x4 acc[FM][FN] = {};

  const int rloc = lane >> 2;
  const int scol = (((lane & 3) ^ (rloc & 3))) * 8;
  const bf16* aSrc = A  + (size_t)(bm + wid * CA * 16 + rloc) * K + scol;
  const bf16* bSrc = Bt + (size_t)(bn + wid * CB * 16 + rloc) * K + scol;

  #define STAGE_DP(buf, kt)                                                   \
    do {                                                                      \
      _Pragma("unroll")                                                       \
      for (int i = 0; i < CA; ++i)                                            \
        GLOAD16(aSrc + (size_t)(i * 16) * K + (kt) * 32,                      \
                &As[buf][(wid * CA + i) * 16][0]);                            \
      _Pragma("unroll")                                                       \
      for (int i = 0; i < CB; ++i)                                            \
        GLOAD16(bSrc + (size_t)(i * 16) * K + (kt) * 32,                      \
                &Bs[buf][(wid * CB + i) * 16][0]);                            \
    } while (0)

  const int NT = K >> 5;
  const int kc = (g ^ (lr & 3)) * 8;

  STAGE_DP(0, 0);
  STAGE_DP(1, 1);

  for (int t = 0; t < NT; ++t) {
    const int buf = t & 3;
    if (t + 2 < NT) {
      STAGE_DP((t + 2) & 3, t + 2);
      asm volatile("s_waitcnt vmcnt(8)" ::: "memory");
    } else if (t + 1 < NT) {
      asm volatile("s_waitcnt vmcnt(4)" ::: "memory");
    } else {
      asm volatile("s_waitcnt vmcnt(0)" ::: "memory");
    }
    __builtin_amdgcn_s_barrier();
    asm volatile("" ::: "memory");

    bf16x8 af[FM], bfv[FN];
    #pragma unroll
    for (int m = 0; m < FM; ++m)
      af[m] = *(const bf16x8*)&As[buf][wr * WROWS + m * 16 + lr][kc];
    #pragma unroll
    for (int n = 0; n < FN; ++n)
      bfv[n] = *(const bf16x8*)&Bs[buf][wc * WCOLS + n * 16 + lr][kc];

    __builtin_amdgcn_s_setprio(1);
    #pragma unroll
    for (int m = 0; m < FM; ++m)
      #pragma unroll
      for (int n = 0; n < FN; ++n)
        acc[m][n] = __builtin_amdgcn_mfma_f32_16x16x32_bf16(af[m], bfv[n], acc[m][n], 0, 0, 0);
    __builtin_amdgcn_s_setprio(0);
  }
  #undef STAGE_DP

  const int orow = g * 4;
  #pragma unroll
  for (int n = 0; n < FN; ++n) {
    const int gn = bn + wc * WCOLS + n * 16 + lr;
    const float bv = bias[gn];
    #pragma unroll
    for (int m = 0; m < FM; ++m) {
      const int gm0 = bm + wr * WROWS + m * 16 + orow;
      if (MODE == 0) {
        #pragma unroll
        for (int r = 0; r < 4; ++r)
          ((float*)out0)[(size_t)(gm0 + r) * N + gn] = acc[m][n][r] + bv;
      }
    }
  }
}

// ---------------- windowed flash attention (MFMA) ----------------

__global__ __launch_bounds__(256) void attn_mfma_k(const bf16* __restrict__ qk,
                                                   const bf16* __restrict__ vt,
                                                   bf16* __restrict__ y) {
  const int q0 = blockIdx.x * 64;
  const int h  = blockIdx.y;
  const int b  = blockIdx.z;
  const int tid  = threadIdx.x;
  const int wid  = tid >> 6;
  const int lane = tid & 63;
  const int lr = lane & 15;
  const int g  = lane >> 4;

  __shared__ bf16 Ks[64][72];
  __shared__ bf16 Vs[64][72];
  __shared__ bf16 Ps[4][16][72];

  const int qrow = q0 + wid * 16 + lr;
  const bf16* qptr = qk + ((size_t)(b * T_ + qrow)) * (2 * C_) + h * HD_;
  bf16x8 qf[2];
  qf[0] = *(const bf16x8*)(qptr + g * 8);
  qf[1] = *(const bf16x8*)(qptr + 32 + g * 8);

  float m = -1e30f, l = 0.f;
  f32x4 yacc[4] = {};

  const int kt_lo = (blockIdx.x >= 4) ? (int)blockIdx.x - 4 : 0;
  for (int kt = kt_lo; kt <= (int)blockIdx.x; ++kt) {
    __syncthreads();
    #pragma unroll
    for (int i = 0; i < 2; ++i) {
      int cc = tid + i * 256;
      int rr = cc >> 3;
      int c0 = (cc & 7) * 8;
      *(bf16x8*)&Ks[rr][c0] = *(const bf16x8*)&qk[((size_t)(b * T_) + kt * 64 + rr) * (2 * C_) + C_ + h * HD_ + c0];
      *(bf16x8*)&Vs[rr][c0] = *(const bf16x8*)&vt[(((size_t)b * H_ + h) * HD_ + rr) * T_ + kt * 64 + c0];
    }
    __syncthreads();

    f32x4 sacc[4] = {};
    #pragma unroll
    for (int t = 0; t < 4; ++t)
      #pragma unroll
      for (int s = 0; s < 2; ++s)
        sacc[t] = __builtin_amdgcn_mfma_f32_16x16x32_bf16(
            *(const bf16x8*)&Ks[t * 16 + lr][s * 32 + g * 8], qf[s], sacc[t], 0, 0, 0);

    float pv[4][4];
    float rmax = -1e30f;
    #pragma unroll
    for (int t = 0; t < 4; ++t)
      #pragma unroll
      for (int r = 0; r < 4; ++r) {
        const int key = kt * 64 + t * 16 + g * 4 + r;
        const bool valid = (key <= qrow) && (qrow - key <= WIN_);
        const float sv = valid ? sacc[t][r] * 0.125f : -__builtin_inff();
        pv[t][r] = sv;
        rmax = fmaxf(rmax, sv);
      }
    rmax = fmaxf(rmax, __shfl_xor(rmax, 16));
    rmax = fmaxf(rmax, __shfl_xor(rmax, 32));

    const float mnew = fmaxf(m, rmax);
    const float alpha = __expf(m - mnew);
    m = mnew;
    float lsum = 0.f;
    #pragma unroll
    for (int t = 0; t < 4; ++t)
      #pragma unroll
      for (int r = 0; r < 4; ++r) {
        const float e = __expf(pv[t][r] - mnew);
        pv[t][r] = e;
        lsum += e;
      }
    lsum += __shfl_xor(lsum, 16);
    lsum += __shfl_xor(lsum, 32);
    l = l * alpha + lsum;

    #pragma unroll
    for (int t = 0; t < 4; ++t) {
      bf16x4 pk;
      #pragma unroll
      for (int r = 0; r < 4; ++r) pk[r] = (bf16)pv[t][r];
      *(bf16x4*)&Ps[wid][lr][t * 16 + g * 4] = pk;
    }

    float al[4];
    #pragma unroll
    for (int r = 0; r < 4; ++r) al[r] = __shfl(alpha, g * 4 + r);
    #pragma unroll
    for (int t = 0; t < 4; ++t)
      #pragma unroll
      for (int r = 0; r < 4; ++r) yacc[t][r] *= al[r];

    bf16x8 pf[2];
    pf[0] = *(const bf16x8*)&Ps[wid][lr][g * 8];
    pf[1] = *(const bf16x8*)&Ps[wid][lr][32 + g * 8];
    #pragma unroll
    for (int t = 0; t < 4; ++t)
      #pragma unroll
      for (int s = 0; s < 2; ++s)
        yacc[t] = __builtin_amdgcn_mfma_f32_16x16x32_bf16(
            pf[s], *(const bf16x8*)&Vs[t * 16 + lr][s * 32 + g * 8], yacc[t], 0, 0, 0);
  }

  float li[4];
  #pragma unroll
  for (int r = 0; r < 4; ++r) li[r] = 1.f / __shfl(l, g * 4 + r);
  #pragma unroll
  for (int t = 0; t < 4; ++t)
    #pragma unroll
    for (int r = 0; r < 4; ++r) {
      const int tok = q0 + wid * 16 + g * 4 + r;
      y[((size_t)(b * T_ + tok)) * C_ + h * HD_ + t * 16 + lr] = (bf16)(yacc[t][r] * li[r]);
    }
}

// ---------------- launch ----------------

extern "C" void kernel_launch(void* const* d_in, const int* in_sizes, int n_in,
                              void* d_out, int out_size, void* d_ws, size_t ws_size,
                              hipStream_t stream) {
  const float* x     = (const float*)d_in[0];
  const float* Wqkv  = (const float*)d_in[1];
  const float* bqkv  = (const float*)d_in[2];
  const float* Wproj = (const float*)d_in[3];
  const float* bproj = (const float*)d_in[4];
  float* out = (float*)d_out;

  const size_t SZ_QK  = (size_t)B_ * T_ * 2 * C_ * sizeof(bf16);
  const size_t SZ_VT  = (size_t)B_ * H_ * HD_ * T_ * sizeof(bf16);
  const size_t SZ_XB  = (size_t)B_ * T_ * C_ * sizeof(bf16);
  const size_t SZ_WQT = (size_t)3 * C_ * C_ * sizeof(bf16);
  const size_t SZ_WPT = (size_t)C_ * C_ * sizeof(bf16);
  const size_t NEED   = SZ_QK + SZ_VT + SZ_XB + SZ_WQT + SZ_WPT + SZ_XB;
  if (ws_size < NEED) return;

  char* ws = (char*)d_ws;
  bf16* qkb    = (bf16*)(ws);
  bf16* vtb    = (bf16*)(ws + SZ_QK);
  bf16* xb     = (bf16*)(ws + SZ_QK + SZ_VT);
  bf16* wqkvT  = (bf16*)(ws + SZ_QK + SZ_VT + SZ_XB);
  bf16* wprojT = (bf16*)(ws + SZ_QK + SZ_VT + SZ_XB + SZ_WQT);
  bf16* yb     = (bf16*)(ws + SZ_QK + SZ_VT + SZ_XB + SZ_WQT + SZ_WPT);

  cvt_f32_bf16_k<<<4096, 256, 0, stream>>>(x, xb);
  transpose_cvt_k<<<dim3(3 * C_ / 32, C_ / 32), dim3(32, 8), 0, stream>>>(Wqkv, wqkvT, C_, 3 * C_);
  transpose_cvt_k<<<dim3(C_ / 32, C_ / 32), dim3(32, 8), 0, stream>>>(Wproj, wprojT, C_, C_);

  // qkv = x @ Wqkv + bqkv : 256x192 tiles -> 16x16 = 256 blocks (full fill)
  gemm8p_k<2><<<dim3((B_ * T_) / 256, (3 * C_) / 192), 512, 0, stream>>>(
      xb, wqkvT, bqkv, qkb, vtb, B_ * T_, 3 * C_, C_);

  attn_mfma_k<<<dim3(T_ / 64, H_, B_), 256, 0, stream>>>(qkb, vtb, yb);

  gemm_dp_k<128, 128, 2, 2, 0><<<dim3((B_ * T_) / 128, C_ / 128), 256, 0, stream>>>(
      yb, wprojT, bproj, out, nullptr, B_ * T_, C_, C_);
}

// Round 9
// 84.922 us; speedup vs baseline: 2.2065x; 1.1015x over previous
//
#include <hip/hip_runtime.h>
#include <hip/hip_bf16.h>
#include <math.h>

typedef __bf16 bf16;
typedef __attribute__((ext_vector_type(8))) __bf16 bf16x8;
typedef __attribute__((ext_vector_type(4))) __bf16 bf16x4;
typedef __attribute__((ext_vector_type(4))) float f32x4;

#define B_  2
#define T_  2048
#define C_  1024
#define H_  16
#define HD_ 64
#define WIN_ 256

// async global->LDS, 16B per lane, dest = wave-uniform base + lane*16
#define GLOAD16(g, l)                                                        \
  __builtin_amdgcn_global_load_lds(                                          \
      (const __attribute__((address_space(1))) void*)(g),                    \
      (__attribute__((address_space(3))) void*)(l), 16, 0, 0)

__device__ inline void bar() {
  asm volatile("" ::: "memory");
  __builtin_amdgcn_s_barrier();
  asm volatile("" ::: "memory");
}

// ---------------- conversions ----------------

__global__ __launch_bounds__(256) void cvt_f32_bf16_k(const float* __restrict__ in,
                                                      bf16* __restrict__ out) {
  int idx = blockIdx.x * 256 + threadIdx.x;
  const float4 v = ((const float4*)in)[idx];
  bf16x4 o;
  o[0] = (bf16)v.x; o[1] = (bf16)v.y; o[2] = (bf16)v.z; o[3] = (bf16)v.w;
  ((bf16x4*)out)[idx] = o;
}

__global__ __launch_bounds__(256) void transpose_cvt_k(const float* __restrict__ W,
                                                       bf16* __restrict__ WT,
                                                       int K, int N) {
  __shared__ float t[32][33];
  int n0 = blockIdx.x * 32, k0 = blockIdx.y * 32;
  int tx = threadIdx.x, ty = threadIdx.y;
  #pragma unroll
  for (int i = 0; i < 32; i += 8)
    t[ty + i][tx] = W[(size_t)(k0 + ty + i) * N + (n0 + tx)];
  __syncthreads();
  #pragma unroll
  for (int i = 0; i < 32; i += 8)
    WT[(size_t)(n0 + ty + i) * K + (k0 + tx)] = (bf16)t[tx][ty + i];
}

// ---------------- double-buffered MFMA GEMM, sized for 2 blocks/CU ----------------
// C = A[M][K] * Bt[N][K]^T + bias. BK=64, TMxTN tile, WMxWN waves.
// LDS = (TM+TN)*64*2B*2buf; counted vmcnt(CPW); 2 barriers per K-tile;
// XOR-swizzle (inverse on global src, forward on ds_read col).
// MODE 0: f32 out stride N.
// MODE 2: qkv split: cols [0,2C) -> bf16 out0 stride 2C;
//                    cols [2C,3C) -> V^T layout out1[((b*H+h)*64+d)*T+tok].

template <int TM, int TN, int WM, int WN, int MINW, int MODE>
__global__ __launch_bounds__(WM * WN * 64, MINW)
void gemm_db_k(const bf16* __restrict__ A, const bf16* __restrict__ Bt,
               const float* __restrict__ bias,
               void* __restrict__ out0, void* __restrict__ out1,
               int M, int N, int K) {
  constexpr int NW    = WM * WN;
  constexpr int WROWS = TM / WM;
  constexpr int WCOLS = TN / WN;
  constexpr int FM    = WROWS / 16;
  constexpr int FN    = WCOLS / 16;
  constexpr int NCH   = (TM + TN) / 8;   // 1KB staging chunks per K-tile
  constexpr int CPW   = NCH / NW;        // chunks per wave

  const int bm = blockIdx.x * TM;
  const int bn = blockIdx.y * TN;
  const int tid  = threadIdx.x;
  const int wid  = tid >> 6;
  const int lane = tid & 63;
  const int wr = wid / WN;
  const int wc = wid % WN;
  const int lr = lane & 15;
  const int g  = lane >> 4;

  __shared__ bf16 As[2][TM * 64];
  __shared__ bf16 Bs[2][TN * 64];

  f32x4 acc[FM][FN] = {};

  // staging: 1KB chunk = 8 rows x 128B; lane -> row lane>>3,
  // global 16B piece (lane&7)^(lane>>3); LDS dest linear.
  const int sr = lane >> 3;
  const int sc = ((lane & 7) ^ sr) << 3;

  #define STG(p_, u_)                                                        \
    do {                                                                     \
      _Pragma("unroll")                                                      \
      for (int i = 0; i < CPW; ++i) {                                        \
        const int c = wid * CPW + i;                                         \
        if (c < TM / 8) {                                                    \
          GLOAD16(A + (size_t)(bm + c * 8 + sr) * K + (u_) * 64 + sc,        \
                  &As[p_][c * 8 * 64]);                                      \
        } else {                                                             \
          GLOAD16(Bt + (size_t)(bn + (c - TM / 8) * 8 + sr) * K + (u_) * 64 + sc, \
                  &Bs[p_][(c - TM / 8) * 8 * 64]);                           \
        }                                                                    \
      }                                                                      \
    } while (0)

  const int NT = K >> 6;
  // read-side swizzle: LDS[r][j16] = global[r][j16 ^ (r&7)]; frag rows have r&7==lr&7
  const int kc0 = ((0 + g) ^ (lr & 7)) << 3;
  const int kc1 = ((4 + g) ^ (lr & 7)) << 3;

  STG(0, 0);
  asm volatile("s_waitcnt vmcnt(0)" ::: "memory");
  __builtin_amdgcn_s_barrier();
  asm volatile("" ::: "memory");

  for (int u = 0; u < NT; ++u) {
    const int p = u & 1;
    if (u + 1 < NT) {
      STG(p ^ 1, u + 1);
      asm volatile("s_waitcnt vmcnt(%0)" :: "i"(CPW) : "memory"); // tile u landed
    } else {
      asm volatile("s_waitcnt vmcnt(0)" ::: "memory");
    }
    bar();

    const bf16* Ar = &As[p][(wr * WROWS + lr) * 64];
    const bf16* Br = &Bs[p][(wc * WCOLS + lr) * 64];
    #pragma unroll
    for (int s = 0; s < 2; ++s) {
      const int kc = s ? kc1 : kc0;
      bf16x8 av[FM], bvv[FN];
      #pragma unroll
      for (int m = 0; m < FM; ++m)
        av[m] = *(const bf16x8*)(Ar + m * 16 * 64 + kc);
      #pragma unroll
      for (int n = 0; n < FN; ++n)
        bvv[n] = *(const bf16x8*)(Br + n * 16 * 64 + kc);
      __builtin_amdgcn_s_setprio(1);
      #pragma unroll
      for (int m = 0; m < FM; ++m)
        #pragma unroll
        for (int n = 0; n < FN; ++n)
          acc[m][n] = __builtin_amdgcn_mfma_f32_16x16x32_bf16(av[m], bvv[n], acc[m][n], 0, 0, 0);
      __builtin_amdgcn_s_setprio(0);
    }
    bar();
  }
  #undef STG

  // epilogue: D elem (reg r, lane l) -> row=(l>>4)*4+r, col=l&15
  const int orow = g * 4;
  #pragma unroll
  for (int n = 0; n < FN; ++n) {
    const int nbase = bn + wc * WCOLS + n * 16;
    const int gn = nbase + lr;
    const float bv_ = bias[gn];
    #pragma unroll
    for (int m = 0; m < FM; ++m) {
      const int gm0 = bm + wr * WROWS + m * 16 + orow;
      if (MODE == 0) {
        #pragma unroll
        for (int r = 0; r < 4; ++r)
          ((float*)out0)[(size_t)(gm0 + r) * N + gn] = acc[m][n][r] + bv_;
      } else { // MODE 2
        if (nbase < 2 * C_) {
          #pragma unroll
          for (int r = 0; r < 4; ++r)
            ((bf16*)out0)[(size_t)(gm0 + r) * (2 * C_) + gn] = (bf16)(acc[m][n][r] + bv_);
        } else {
          const int vcol = gn - 2 * C_;
          const int h = vcol >> 6, d = vcol & 63;
          const int b = gm0 >> 11, tok = gm0 & (T_ - 1);   // gm0 % 4 == 0
          bf16x4 o;
          #pragma unroll
          for (int r = 0; r < 4; ++r) o[r] = (bf16)(acc[m][n][r] + bv_);
          *(bf16x4*)&((bf16*)out1)[(((size_t)b * H_ + h) * HD_ + d) * T_ + tok] = o;
        }
      }
    }
  }
}

// ---------------- windowed flash attention (MFMA) ----------------

__global__ __launch_bounds__(256) void attn_mfma_k(const bf16* __restrict__ qk,
                                                   const bf16* __restrict__ vt,
                                                   bf16* __restrict__ y) {
  const int q0 = blockIdx.x * 64;
  const int h  = blockIdx.y;
  const int b  = blockIdx.z;
  const int tid  = threadIdx.x;
  const int wid  = tid >> 6;
  const int lane = tid & 63;
  const int lr = lane & 15;
  const int g  = lane >> 4;

  __shared__ bf16 Ks[64][72];
  __shared__ bf16 Vs[64][72];
  __shared__ bf16 Ps[4][16][72];

  const int qrow = q0 + wid * 16 + lr;
  const bf16* qptr = qk + ((size_t)(b * T_ + qrow)) * (2 * C_) + h * HD_;
  bf16x8 qf[2];
  qf[0] = *(const bf16x8*)(qptr + g * 8);
  qf[1] = *(const bf16x8*)(qptr + 32 + g * 8);

  float m = -1e30f, l = 0.f;
  f32x4 yacc[4] = {};

  const int kt_lo = (blockIdx.x >= 4) ? (int)blockIdx.x - 4 : 0;
  for (int kt = kt_lo; kt <= (int)blockIdx.x; ++kt) {
    __syncthreads();
    #pragma unroll
    for (int i = 0; i < 2; ++i) {
      int cc = tid + i * 256;
      int rr = cc >> 3;
      int c0 = (cc & 7) * 8;
      *(bf16x8*)&Ks[rr][c0] = *(const bf16x8*)&qk[((size_t)(b * T_) + kt * 64 + rr) * (2 * C_) + C_ + h * HD_ + c0];
      *(bf16x8*)&Vs[rr][c0] = *(const bf16x8*)&vt[(((size_t)b * H_ + h) * HD_ + rr) * T_ + kt * 64 + c0];
    }
    __syncthreads();

    f32x4 sacc[4] = {};
    #pragma unroll
    for (int t = 0; t < 4; ++t)
      #pragma unroll
      for (int s = 0; s < 2; ++s)
        sacc[t] = __builtin_amdgcn_mfma_f32_16x16x32_bf16(
            *(const bf16x8*)&Ks[t * 16 + lr][s * 32 + g * 8], qf[s], sacc[t], 0, 0, 0);

    float pv[4][4];
    float rmax = -1e30f;
    #pragma unroll
    for (int t = 0; t < 4; ++t)
      #pragma unroll
      for (int r = 0; r < 4; ++r) {
        const int key = kt * 64 + t * 16 + g * 4 + r;
        const bool valid = (key <= qrow) && (qrow - key <= WIN_);
        const float sv = valid ? sacc[t][r] * 0.125f : -__builtin_inff();
        pv[t][r] = sv;
        rmax = fmaxf(rmax, sv);
      }
    rmax = fmaxf(rmax, __shfl_xor(rmax, 16));
    rmax = fmaxf(rmax, __shfl_xor(rmax, 32));

    const float mnew = fmaxf(m, rmax);
    const float alpha = __expf(m - mnew);
    m = mnew;
    float lsum = 0.f;
    #pragma unroll
    for (int t = 0; t < 4; ++t)
      #pragma unroll
      for (int r = 0; r < 4; ++r) {
        const float e = __expf(pv[t][r] - mnew);
        pv[t][r] = e;
        lsum += e;
      }
    lsum += __shfl_xor(lsum, 16);
    lsum += __shfl_xor(lsum, 32);
    l = l * alpha + lsum;

    #pragma unroll
    for (int t = 0; t < 4; ++t) {
      bf16x4 pk;
      #pragma unroll
      for (int r = 0; r < 4; ++r) pk[r] = (bf16)pv[t][r];
      *(bf16x4*)&Ps[wid][lr][t * 16 + g * 4] = pk;
    }

    float al[4];
    #pragma unroll
    for (int r = 0; r < 4; ++r) al[r] = __shfl(alpha, g * 4 + r);
    #pragma unroll
    for (int t = 0; t < 4; ++t)
      #pragma unroll
      for (int r = 0; r < 4; ++r) yacc[t][r] *= al[r];

    bf16x8 pf[2];
    pf[0] = *(const bf16x8*)&Ps[wid][lr][g * 8];
    pf[1] = *(const bf16x8*)&Ps[wid][lr][32 + g * 8];
    #pragma unroll
    for (int t = 0; t < 4; ++t)
      #pragma unroll
      for (int s = 0; s < 2; ++s)
        yacc[t] = __builtin_amdgcn_mfma_f32_16x16x32_bf16(
            pf[s], *(const bf16x8*)&Vs[t * 16 + lr][s * 32 + g * 8], yacc[t], 0, 0, 0);
  }

  float li[4];
  #pragma unroll
  for (int r = 0; r < 4; ++r) li[r] = 1.f / __shfl(l, g * 4 + r);
  #pragma unroll
  for (int t = 0; t < 4; ++t)
    #pragma unroll
    for (int r = 0; r < 4; ++r) {
      const int tok = q0 + wid * 16 + g * 4 + r;
      y[((size_t)(b * T_ + tok)) * C_ + h * HD_ + t * 16 + lr] = (bf16)(yacc[t][r] * li[r]);
    }
}

// ---------------- launch ----------------

extern "C" void kernel_launch(void* const* d_in, const int* in_sizes, int n_in,
                              void* d_out, int out_size, void* d_ws, size_t ws_size,
                              hipStream_t stream) {
  const float* x     = (const float*)d_in[0];
  const float* Wqkv  = (const float*)d_in[1];
  const float* bqkv  = (const float*)d_in[2];
  const float* Wproj = (const float*)d_in[3];
  const float* bproj = (const float*)d_in[4];
  float* out = (float*)d_out;

  const size_t SZ_QK  = (size_t)B_ * T_ * 2 * C_ * sizeof(bf16);
  const size_t SZ_VT  = (size_t)B_ * H_ * HD_ * T_ * sizeof(bf16);
  const size_t SZ_XB  = (size_t)B_ * T_ * C_ * sizeof(bf16);
  const size_t SZ_WQT = (size_t)3 * C_ * C_ * sizeof(bf16);
  const size_t SZ_WPT = (size_t)C_ * C_ * sizeof(bf16);
  const size_t NEED   = SZ_QK + SZ_VT + SZ_XB + SZ_WQT + SZ_WPT + SZ_XB;
  if (ws_size < NEED) return;

  char* ws = (char*)d_ws;
  bf16* qkb    = (bf16*)(ws);
  bf16* vtb    = (bf16*)(ws + SZ_QK);
  bf16* xb     = (bf16*)(ws + SZ_QK + SZ_VT);
  bf16* wqkvT  = (bf16*)(ws + SZ_QK + SZ_VT + SZ_XB);
  bf16* wprojT = (bf16*)(ws + SZ_QK + SZ_VT + SZ_XB + SZ_WQT);
  bf16* yb     = (bf16*)(ws + SZ_QK + SZ_VT + SZ_XB + SZ_WQT + SZ_WPT);

  cvt_f32_bf16_k<<<4096, 256, 0, stream>>>(x, xb);
  transpose_cvt_k<<<dim3(3 * C_ / 32, C_ / 32), dim3(32, 8), 0, stream>>>(Wqkv, wqkvT, C_, 3 * C_);
  transpose_cvt_k<<<dim3(C_ / 32, C_ / 32), dim3(32, 8), 0, stream>>>(Wproj, wprojT, C_, C_);

  // qkv: 128x192 tiles, 8 waves, LDS 80KB -> 2 blocks/CU; grid 32x16=512
  gemm_db_k<128, 192, 2, 4, 4, 2><<<dim3((B_ * T_) / 128, (3 * C_) / 192), 512, 0, stream>>>(
      xb, wqkvT, bqkv, qkb, vtb, B_ * T_, 3 * C_, C_);

  attn_mfma_k<<<dim3(T_ / 64, H_, B_), 256, 0, stream>>>(qkb, vtb, yb);

  // proj: 64x128 tiles, 4 waves, LDS 48KB; grid 64x8=512 -> 2 blocks/CU
  gemm_db_k<64, 128, 2, 2, 2, 0><<<dim3((B_ * T_) / 64, C_ / 128), 256, 0, stream>>>(
      yb, wprojT, bproj, out, nullptr, B_ * T_, C_, C_);
}